// Round 10
// baseline (2232.084 us; speedup 1.0000x reference)
//
#include <hip/hip_runtime.h>

#define VOCAB 32000
#define EMB   1024
#define HID   1024
#define SEQ   128
#define BATCH 32
#define ROWS  (SEQ * BATCH)   // 4096
#define G4    (4 * HID)       // 4096
#define LSLOT 32768           // ushorts per ring slot (32 rows x 1024)

typedef __bf16 bf16x8 __attribute__((ext_vector_type(8)));
typedef float  f32x4  __attribute__((ext_vector_type(4)));

__device__ __forceinline__ unsigned short f2bf(float f) {
  union { float f; unsigned int u; } v; v.f = f;
  unsigned int r = v.u + 0x7fffu + ((v.u >> 16) & 1u);
  return (unsigned short)(r >> 16);
}
__device__ __forceinline__ float bf2f(unsigned short u) {
  union { unsigned int u; float f; } v; v.u = ((unsigned int)u) << 16;
  return v.f;
}

__device__ __forceinline__ void async16(const void* g, void* l) {
  __builtin_amdgcn_global_load_lds(
      (const __attribute__((address_space(1))) void*)g,
      (__attribute__((address_space(3))) void*)l, 16, 0, 0);
}

// ---------------- embedding gather + f32 -> (bf16 hi, bf16 lo) ----------------
__global__ void embed_split(const int* __restrict__ ids, const float* __restrict__ emb,
                            unsigned short* __restrict__ Xhi, unsigned short* __restrict__ Xlo) {
  int r = blockIdx.x;
  int row = ids[r];
  int e = threadIdx.x * 4;
  const float4 v = *reinterpret_cast<const float4*>(emb + (size_t)row * EMB + e);
  ushort4 hi, lo;
  hi.x = f2bf(v.x); lo.x = f2bf(v.x - bf2f(hi.x));
  hi.y = f2bf(v.y); lo.y = f2bf(v.y - bf2f(hi.y));
  hi.z = f2bf(v.z); lo.z = f2bf(v.z - bf2f(hi.z));
  hi.w = f2bf(v.w); lo.w = f2bf(v.w - bf2f(hi.w));
  *reinterpret_cast<ushort4*>(Xhi + (size_t)r * EMB + e) = hi;
  *reinterpret_cast<ushort4*>(Xlo + (size_t)r * EMB + e) = lo;
}

// ------------- transpose+split f32 [K][N] -> bf16 hi/lo [N][K] -------------
__global__ void wsplit_kernel(const float* __restrict__ in, unsigned short* __restrict__ hi,
                              unsigned short* __restrict__ lo, int K, int N) {
  __shared__ float t[32][33];
  int n0 = blockIdx.x * 32, k0 = blockIdx.y * 32;
  int tx = threadIdx.x, ty = threadIdx.y;
#pragma unroll
  for (int i = 0; i < 4; ++i)
    t[ty + i * 8][tx] = in[(size_t)(k0 + ty + i * 8) * N + n0 + tx];
  __syncthreads();
#pragma unroll
  for (int i = 0; i < 4; ++i) {
    float v = t[tx][ty + i * 8];
    unsigned short h = f2bf(v);
    hi[(size_t)(n0 + ty + i * 8) * K + k0 + tx] = h;
    lo[(size_t)(n0 + ty + i * 8) * K + k0 + tx] = f2bf(v - bf2f(h));
  }
}

// ------------- transpose f32 [K][N] -> bf16 [N][K] (Wd, r5-validated) -------
__global__ void transpose_kernel(const float* __restrict__ in, unsigned short* __restrict__ out,
                                 int K, int N) {
  __shared__ float t[32][33];
  int n0 = blockIdx.x * 32, k0 = blockIdx.y * 32;
  int tx = threadIdx.x, ty = threadIdx.y;
#pragma unroll
  for (int i = 0; i < 4; ++i)
    t[ty + i * 8][tx] = in[(size_t)(k0 + ty + i * 8) * N + n0 + tx];
  __syncthreads();
#pragma unroll
  for (int i = 0; i < 4; ++i)
    out[(size_t)(n0 + ty + i * 8) * K + k0 + tx] = f2bf(t[tx][ty + i * 8]);
}

// ============ fused 2-layer LSTM: register-resident split-bf16 W, MFMA z-path,
// ring-buffer h exchange + per-block FLAG sync (parallel stores, no atomic RMW).
// blocks 0..127 layer0, 128..255 layer1. F0/F1: 128 flags, 16B padded.
__global__ __launch_bounds__(512, 2) void lstm_ring(
    const unsigned short* __restrict__ Xhi, const unsigned short* __restrict__ Xlo,
    const unsigned short* __restrict__ W0hi, const unsigned short* __restrict__ W0lo,
    const unsigned short* __restrict__ W1hi, const unsigned short* __restrict__ W1lo,
    const float* __restrict__ b0, const float* __restrict__ b1,
    unsigned short* h1hi, unsigned short* h1lo,   // rings [129][32][1024]
    unsigned short* h2hi, unsigned short* h2lo,   // h2hi ring slot t+1 == H2 row-block t
    unsigned int* F0, unsigned int* F1)
{
  __shared__ float zl[8][32][36];            // 36 KB, padded stride vs bank conflicts

  const int tid   = threadIdx.x;
  const int lane  = tid & 63;
  const int w     = tid >> 6;                // wave 0..7, K-range w*256..+256
  const int layer = blockIdx.x >> 7;
  const int wg    = blockIdx.x & 127;
  const int j0    = wg * 8;
  const int lrow  = lane & 15;
  const int klo   = (lane >> 4) * 8;

  const unsigned short* Whi = layer ? W1hi : W0hi;
  const unsigned short* Wlo = layer ? W1lo : W0lo;
  const float*          bias = layer ? b1 : b0;

  // ---- persistent W fragments (hi+lo, 128 VGPRs) ----
  bf16x8 wh[2][8], wl[2][8];
#pragma unroll
  for (int nt = 0; nt < 2; ++nt) {
    int n = nt * 16 + lrow;
    size_t grow = (size_t)((n >> 3) * 1024 + j0 + (n & 7));
    const unsigned short* bh = Whi + grow * 2048 + w * 256 + klo;
    const unsigned short* bl = Wlo + grow * 2048 + w * 256 + klo;
#pragma unroll
    for (int ks = 0; ks < 8; ++ks) {
      wh[nt][ks] = *reinterpret_cast<const bf16x8*>(bh + ks * 32);
      wl[nt][ks] = *reinterpret_cast<const bf16x8*>(bl + ks * 32);
    }
  }

  const int eb = tid >> 3;
  const int ec = tid & 7;
  const float bi  = bias[j0 + ec];
  const float bj  = bias[1024 + j0 + ec];
  const float bff = bias[2048 + j0 + ec];
  const float bo  = bias[3072 + j0 + ec];
  float c = 0.f;

  unsigned int* Fown = layer ? F1 : F0;

  for (int t = 0; t < SEQ; ++t) {
    // ---- per-wave dependency wait (parallel flag polls, no RMW) ----
    {
      const unsigned int* FF;
      unsigned tgt;
      if (layer == 0) { FF = F0; tgt = (w < 4) ? 0u : (unsigned)t; }
      else { FF = (w < 4) ? F0 : F1; tgt = (w < 4) ? (unsigned)(t + 1) : (unsigned)t; }
      if (tgt) {
        for (;;) {
          unsigned v0 = __hip_atomic_load(FF + lane * 4, __ATOMIC_RELAXED,
                                          __HIP_MEMORY_SCOPE_AGENT);
          unsigned v1 = __hip_atomic_load(FF + (64 + lane) * 4, __ATOMIC_RELAXED,
                                          __HIP_MEMORY_SCOPE_AGENT);
          if (__all((v0 >= tgt) && (v1 >= tgt))) break;
          __builtin_amdgcn_s_sleep(2);
        }
      }
      __builtin_amdgcn_sched_barrier(0);   // pin: A-loads stay after the poll
    }

    // ---- A sources (ring slots written-once, read-fresh) ----
    const unsigned short *aHi, *aLo;
    if (layer == 0) {
      if (w < 4) { aHi = Xhi + (size_t)t * LSLOT;        aLo = Xlo + (size_t)t * LSLOT; }
      else       { aHi = h1hi + (size_t)t * LSLOT;       aLo = h1lo + (size_t)t * LSLOT; }
    } else {
      if (w < 4) { aHi = h1hi + (size_t)(t + 1) * LSLOT; aLo = h1lo + (size_t)(t + 1) * LSLOT; }
      else       { aHi = h2hi + (size_t)t * LSLOT;       aLo = h2lo + (size_t)t * LSLOT; }
    }
    const int aoff = (w & 3) * 256;
    const unsigned short* aH0 = aHi + (size_t)lrow * 1024 + aoff + klo;
    const unsigned short* aL0 = aLo + (size_t)lrow * 1024 + aoff + klo;
    const unsigned short* aH1 = aH0 + 16 * 1024;
    const unsigned short* aL1 = aL0 + 16 * 1024;

    f32x4 acc[2][2] = {};
#pragma unroll
    for (int ks = 0; ks < 8; ++ks) {
      bf16x8 a0h = *reinterpret_cast<const bf16x8*>(aH0 + ks * 32);
      bf16x8 a0l = *reinterpret_cast<const bf16x8*>(aL0 + ks * 32);
      bf16x8 a1h = *reinterpret_cast<const bf16x8*>(aH1 + ks * 32);
      bf16x8 a1l = *reinterpret_cast<const bf16x8*>(aL1 + ks * 32);
#pragma unroll
      for (int nt = 0; nt < 2; ++nt) {
        acc[0][nt] = __builtin_amdgcn_mfma_f32_16x16x32_bf16(a0h, wh[nt][ks], acc[0][nt], 0, 0, 0);
        acc[0][nt] = __builtin_amdgcn_mfma_f32_16x16x32_bf16(a0l, wh[nt][ks], acc[0][nt], 0, 0, 0);
        acc[0][nt] = __builtin_amdgcn_mfma_f32_16x16x32_bf16(a0h, wl[nt][ks], acc[0][nt], 0, 0, 0);
        acc[1][nt] = __builtin_amdgcn_mfma_f32_16x16x32_bf16(a1h, wh[nt][ks], acc[1][nt], 0, 0, 0);
        acc[1][nt] = __builtin_amdgcn_mfma_f32_16x16x32_bf16(a1l, wh[nt][ks], acc[1][nt], 0, 0, 0);
        acc[1][nt] = __builtin_amdgcn_mfma_f32_16x16x32_bf16(a1h, wl[nt][ks], acc[1][nt], 0, 0, 0);
      }
    }

    // C/D (r5-validated): col = lane&15 (n), row = (lane>>4)*4 + j (batch)
    const int zb = (lane >> 4) * 4;
#pragma unroll
    for (int mt = 0; mt < 2; ++mt)
#pragma unroll
      for (int nt = 0; nt < 2; ++nt)
#pragma unroll
        for (int j = 0; j < 4; ++j)
          zl[w][mt * 16 + zb + j][nt * 16 + lrow] = acc[mt][nt][j];
    __syncthreads();

    if (tid < 256) {
      float iv = bi, jv = bj, fv = bff, ov = bo;
#pragma unroll
      for (int ww = 0; ww < 8; ++ww) {
        iv += zl[ww][eb][ec];
        jv += zl[ww][eb][8 + ec];
        fv += zl[ww][eb][16 + ec];
        ov += zl[ww][eb][24 + ec];
      }
      float si = 1.f / (1.f + expf(-iv));
      float sf = 1.f / (1.f + expf(-(fv + 1.f)));   // FORGET_BIAS = 1.0
      float so = 1.f / (1.f + expf(-ov));
      float tj = tanhf(jv);
      c = c * sf + si * tj;
      float hv = tanhf(c) * so;
      unsigned short hh = f2bf(hv);
      unsigned short hl = f2bf(hv - bf2f(hh));
      int hhp = __shfl_xor((int)hh, 1);
      int hlp = __shfl_xor((int)hl, 1);
      if ((ec & 1) == 0) {
        unsigned uhi = (unsigned)hh | ((unsigned)hhp << 16);
        unsigned ulo = (unsigned)hl | ((unsigned)hlp << 16);
        unsigned off = (unsigned)(eb * 1024 + j0 + ec) >> 1;
        unsigned int* dh = (unsigned int*)((layer ? h2hi : h1hi) + (size_t)(t + 1) * LSLOT) + off;
        unsigned int* dl = (unsigned int*)((layer ? h2lo : h1lo) + (size_t)(t + 1) * LSLOT) + off;
        __hip_atomic_store(dh, uhi, __ATOMIC_RELAXED, __HIP_MEMORY_SCOPE_AGENT);
        __hip_atomic_store(dl, ulo, __ATOMIC_RELAXED, __HIP_MEMORY_SCOPE_AGENT);
      }
    }
    __syncthreads();   // drains all coherent stores + zl reads done
    if (tid == 0)
      __hip_atomic_store(&Fown[wg * 4], (unsigned)(t + 1),
                         __ATOMIC_RELEASE, __HIP_MEMORY_SCOPE_AGENT);
  }
}

// ---------------- MFMA dense GEMM (r5-validated): C = A * B^T + bias ----------
__global__ __launch_bounds__(256) void gemm_bt(
    const unsigned short* __restrict__ A, const unsigned short* __restrict__ B,
    const float* __restrict__ bias, float* __restrict__ C, int M, int N, int K)
{
  __shared__ __align__(16) unsigned short As[128 * 32];
  __shared__ __align__(16) unsigned short Bs[128 * 32];
  const int tid = threadIdx.x, lane = tid & 63, w = tid >> 6;

  const int ntiles = gridDim.x;
  int lid = blockIdx.y * ntiles + blockIdx.x;
  int total = ntiles * gridDim.y;
  int cpx = total >> 3;
  int swz = (lid & 7) * cpx + (lid >> 3);
  int bn = swz % ntiles, bm = swz / ntiles;

  const int wm = (w >> 1) * 64, wn = (w & 1) * 64;
  const int lrow = lane & 15, klo = (lane >> 4) * 8;
  const int l4 = lane >> 2, l2 = lane & 3;

  f32x4 acc[4][4] = {};

  for (int kt = 0; kt < K / 32; ++kt) {
    __syncthreads();
#pragma unroll
    for (int ci = 0; ci < 2; ++ci) {
      int row = w * 32 + ci * 16 + l4;
      async16(A + (size_t)(bm * 128 + row) * K + kt * 32 + l2 * 8,
              (char*)As + (w * 2 + ci) * 1024);
      async16(B + (size_t)(bn * 128 + row) * K + kt * 32 + l2 * 8,
              (char*)Bs + (w * 2 + ci) * 1024);
    }
    __syncthreads();
    bf16x8 a[4], bb[4];
#pragma unroll
    for (int i = 0; i < 4; ++i) {
      a[i]  = *reinterpret_cast<const bf16x8*>(As + (wm + i * 16 + lrow) * 32 + klo);
      bb[i] = *reinterpret_cast<const bf16x8*>(Bs + (wn + i * 16 + lrow) * 32 + klo);
    }
#pragma unroll
    for (int i = 0; i < 4; ++i)
#pragma unroll
      for (int j = 0; j < 4; ++j)
        acc[i][j] = __builtin_amdgcn_mfma_f32_16x16x32_bf16(a[i], bb[j], acc[i][j], 0, 0, 0);
  }

#pragma unroll
  for (int j2 = 0; j2 < 4; ++j2) {
    int col = bn * 128 + wn + j2 * 16 + lrow;
    float bv = bias[col];
#pragma unroll
    for (int i = 0; i < 4; ++i) {
      int rbase = bm * 128 + wm + i * 16 + (lane >> 4) * 4;
#pragma unroll
      for (int j = 0; j < 4; ++j)
        C[(size_t)(rbase + j) * N + col] = acc[i][j2][j] + bv;
    }
  }
}

// ================= host =====================================================
extern "C" void kernel_launch(void* const* d_in, const int* in_sizes, int n_in,
                              void* d_out, int out_size, void* d_ws, size_t ws_size,
                              hipStream_t stream) {
  const int*   ids = (const int*)d_in[0];
  const float* emb = (const float*)d_in[1];
  const float* W0  = (const float*)d_in[2];
  const float* b0  = (const float*)d_in[3];
  const float* W1  = (const float*)d_in[4];
  const float* b1  = (const float*)d_in[5];
  const float* Wd  = (const float*)d_in[6];
  const float* bd  = (const float*)d_in[7];
  float* out = (float*)d_out;

  const size_t ringB = (size_t)(SEQ + 1) * LSLOT * 2;   // 8.45 MB per ring

  // d_out scratch (dead until gemm overwrites all of it): X hi/lo + lo-rings
  unsigned short* Xhi   = (unsigned short*)d_out;
  unsigned short* Xlo   = Xhi + (size_t)ROWS * EMB;
  unsigned short* h1lo  = Xlo + (size_t)ROWS * EMB;
  unsigned short* h2lo  = h1lo + (size_t)(SEQ + 1) * LSLOT;

  char* ws = (char*)d_ws;
  size_t off = 0;
  auto alloc = [&](size_t bytes) {
    char* p = ws + off;
    off += (bytes + 255) & ~(size_t)255;
    return p;
  };
  unsigned int*   F0   = (unsigned int*)alloc(2048);           // 128 flags x 16B
  unsigned int*   F1   = (unsigned int*)alloc(2048);
  unsigned short* h1hi = (unsigned short*)alloc(ringB);
  unsigned short* H2R  = (unsigned short*)alloc(ringB);        // h2-hi ring == H2 output
  size_t regionW = off;
  unsigned short* W0hi = (unsigned short*)alloc((size_t)G4 * 2048 * 2);
  unsigned short* W0lo = (unsigned short*)alloc((size_t)G4 * 2048 * 2);
  unsigned short* W1hi = (unsigned short*)alloc((size_t)G4 * 2048 * 2);
  unsigned short* W1lo = (unsigned short*)alloc((size_t)G4 * 2048 * 2);
  unsigned short* Wdt  = (unsigned short*)(ws + regionW);      // aliases W region post-recurrence
  (void)in_sizes; (void)n_in; (void)out_size; (void)ws_size;   // ws total ~84 MB

  // flag + ring-slot-0 init (host-side, removes in-kernel init barrier)
  hipMemsetAsync(F0, 0, 4096, stream);                         // F0 + F1 (contiguous)
  hipMemsetAsync(h1hi, 0, LSLOT * 2, stream);
  hipMemsetAsync(H2R, 0, LSLOT * 2, stream);
  hipMemsetAsync(h1lo, 0, LSLOT * 2, stream);
  hipMemsetAsync(h2lo, 0, LSLOT * 2, stream);

  embed_split<<<ROWS, 256, 0, stream>>>(ids, emb, Xhi, Xlo);
  wsplit_kernel<<<dim3(G4 / 32, 2048 / 32), dim3(32, 8), 0, stream>>>(W0, W0hi, W0lo, 2048, G4);
  wsplit_kernel<<<dim3(G4 / 32, 2048 / 32), dim3(32, 8), 0, stream>>>(W1, W1hi, W1lo, 2048, G4);

  // ticket-free flag sync needs co-residency only: 256 blocks @ 1/CU -> plain launch OK
  lstm_ring<<<256, 512, 0, stream>>>(Xhi, Xlo, W0hi, W0lo, W1hi, W1lo, b0, b1,
                                     h1hi, h1lo, H2R, h2lo, F0, F1);

  transpose_kernel<<<dim3(VOCAB / 32, HID / 32), dim3(32, 8), 0, stream>>>(Wd, Wdt, HID, VOCAB);
  gemm_bt<<<dim3(VOCAB / 128, ROWS / 128), 256, 0, stream>>>(H2R + LSLOT, Wdt, bd, out,
                                                             ROWS, VOCAB, HID);
}

// Round 11
// 1757.831 us; speedup vs baseline: 1.2698x; 1.2698x over previous
//
#include <hip/hip_runtime.h>

#define VOCAB 32000
#define EMB   1024
#define HID   1024
#define SEQ   128
#define BATCH 32
#define ROWS  (SEQ * BATCH)   // 4096
#define G4    (4 * HID)       // 4096
#define LSLOT 32768           // ushorts per ring slot (32 rows x 1024)

typedef __bf16 bf16x8 __attribute__((ext_vector_type(8)));
typedef float  f32x4  __attribute__((ext_vector_type(4)));

__device__ __forceinline__ unsigned short f2bf(float f) {
  union { float f; unsigned int u; } v; v.f = f;
  unsigned int r = v.u + 0x7fffu + ((v.u >> 16) & 1u);
  return (unsigned short)(r >> 16);
}
__device__ __forceinline__ float bf2f(unsigned short u) {
  union { unsigned int u; float f; } v; v.u = ((unsigned int)u) << 16;
  return v.f;
}

__device__ __forceinline__ void async16(const void* g, void* l) {
  __builtin_amdgcn_global_load_lds(
      (const __attribute__((address_space(1))) void*)g,
      (__attribute__((address_space(3))) void*)l, 16, 0, 0);
}

// fast f32-grade gate functions (v_exp_f32 + v_rcp_f32, ~1e-6 rel err)
__device__ __forceinline__ float fsigmoid(float x) {
  return __builtin_amdgcn_rcpf(1.f + __expf(-x));
}
__device__ __forceinline__ float ftanh(float x) {
  return 1.f - 2.f * __builtin_amdgcn_rcpf(__expf(2.f * x) + 1.f);
}

// ---------------- embedding gather + f32 -> (bf16 hi, bf16 lo) ----------------
__global__ void embed_split(const int* __restrict__ ids, const float* __restrict__ emb,
                            unsigned short* __restrict__ Xhi, unsigned short* __restrict__ Xlo) {
  int r = blockIdx.x;
  int row = ids[r];
  int e = threadIdx.x * 4;
  const float4 v = *reinterpret_cast<const float4*>(emb + (size_t)row * EMB + e);
  ushort4 hi, lo;
  hi.x = f2bf(v.x); lo.x = f2bf(v.x - bf2f(hi.x));
  hi.y = f2bf(v.y); lo.y = f2bf(v.y - bf2f(hi.y));
  hi.z = f2bf(v.z); lo.z = f2bf(v.z - bf2f(hi.z));
  hi.w = f2bf(v.w); lo.w = f2bf(v.w - bf2f(hi.w));
  *reinterpret_cast<ushort4*>(Xhi + (size_t)r * EMB + e) = hi;
  *reinterpret_cast<ushort4*>(Xlo + (size_t)r * EMB + e) = lo;
}

// ------------- transpose+split f32 [K][N] -> bf16 hi/lo [N][K] -------------
__global__ void wsplit_kernel(const float* __restrict__ in, unsigned short* __restrict__ hi,
                              unsigned short* __restrict__ lo, int K, int N) {
  __shared__ float t[32][33];
  int n0 = blockIdx.x * 32, k0 = blockIdx.y * 32;
  int tx = threadIdx.x, ty = threadIdx.y;
#pragma unroll
  for (int i = 0; i < 4; ++i)
    t[ty + i * 8][tx] = in[(size_t)(k0 + ty + i * 8) * N + n0 + tx];
  __syncthreads();
#pragma unroll
  for (int i = 0; i < 4; ++i) {
    float v = t[tx][ty + i * 8];
    unsigned short h = f2bf(v);
    hi[(size_t)(n0 + ty + i * 8) * K + k0 + tx] = h;
    lo[(size_t)(n0 + ty + i * 8) * K + k0 + tx] = f2bf(v - bf2f(h));
  }
}

// ------------- transpose f32 [K][N] -> bf16 [N][K] (Wd, r5-validated) -------
__global__ void transpose_kernel(const float* __restrict__ in, unsigned short* __restrict__ out,
                                 int K, int N) {
  __shared__ float t[32][33];
  int n0 = blockIdx.x * 32, k0 = blockIdx.y * 32;
  int tx = threadIdx.x, ty = threadIdx.y;
#pragma unroll
  for (int i = 0; i < 4; ++i)
    t[ty + i * 8][tx] = in[(size_t)(k0 + ty + i * 8) * N + n0 + tx];
  __syncthreads();
#pragma unroll
  for (int i = 0; i < 4; ++i)
    out[(size_t)(n0 + ty + i * 8) * K + k0 + tx] = f2bf(t[tx][ty + i * 8]);
}

// ============ fused 2-layer LSTM: register-resident split-bf16 W, MFMA z-path,
// ring-buffer h exchange + per-block RELAXED flag sync (no fences anywhere:
// data stores are write-through agent stores drained by the barrier BEFORE the
// flag store is issued, so ordering holds without a release fence).
__global__ __launch_bounds__(512, 2) void lstm_ring(
    const unsigned short* __restrict__ Xhi, const unsigned short* __restrict__ Xlo,
    const unsigned short* __restrict__ W0hi, const unsigned short* __restrict__ W0lo,
    const unsigned short* __restrict__ W1hi, const unsigned short* __restrict__ W1lo,
    const float* __restrict__ b0, const float* __restrict__ b1,
    unsigned short* h1hi, unsigned short* h1lo,   // rings [129][32][1024]
    unsigned short* h2hi, unsigned short* h2lo,   // h2hi ring slot t+1 == H2 row-block t
    unsigned int* F0, unsigned int* F1)
{
  __shared__ float zl[8][32][36];            // 36 KB, padded stride vs bank conflicts

  const int tid   = threadIdx.x;
  const int lane  = tid & 63;
  const int w     = tid >> 6;                // wave 0..7, K-range w*256..+256
  const int layer = blockIdx.x >> 7;
  const int wg    = blockIdx.x & 127;
  const int j0    = wg * 8;
  const int lrow  = lane & 15;
  const int klo   = (lane >> 4) * 8;

  const unsigned short* Whi = layer ? W1hi : W0hi;
  const unsigned short* Wlo = layer ? W1lo : W0lo;
  const float*          bias = layer ? b1 : b0;

  // ---- persistent W fragments (hi+lo, 128 VGPRs) ----
  bf16x8 wh[2][8], wl[2][8];
#pragma unroll
  for (int nt = 0; nt < 2; ++nt) {
    int n = nt * 16 + lrow;
    size_t grow = (size_t)((n >> 3) * 1024 + j0 + (n & 7));
    const unsigned short* bh = Whi + grow * 2048 + w * 256 + klo;
    const unsigned short* bl = Wlo + grow * 2048 + w * 256 + klo;
#pragma unroll
    for (int ks = 0; ks < 8; ++ks) {
      wh[nt][ks] = *reinterpret_cast<const bf16x8*>(bh + ks * 32);
      wl[nt][ks] = *reinterpret_cast<const bf16x8*>(bl + ks * 32);
    }
  }

  const int eb = tid >> 3;
  const int ec = tid & 7;
  const float bi  = bias[j0 + ec];
  const float bj  = bias[1024 + j0 + ec];
  const float bff = bias[2048 + j0 + ec];
  const float bo  = bias[3072 + j0 + ec];
  float c = 0.f;

  unsigned int* Fown = layer ? F1 : F0;

  for (int t = 0; t < SEQ; ++t) {
    // ---- per-wave dependency wait (relaxed flag polls) ----
    {
      const unsigned int* FF;
      unsigned tgt;
      if (layer == 0) { FF = F0; tgt = (w < 4) ? 0u : (unsigned)t; }
      else { FF = (w < 4) ? F0 : F1; tgt = (w < 4) ? (unsigned)(t + 1) : (unsigned)t; }
      if (tgt) {
        for (;;) {
          unsigned v0 = __hip_atomic_load(FF + lane * 4, __ATOMIC_RELAXED,
                                          __HIP_MEMORY_SCOPE_AGENT);
          unsigned v1 = __hip_atomic_load(FF + (64 + lane) * 4, __ATOMIC_RELAXED,
                                          __HIP_MEMORY_SCOPE_AGENT);
          if (__all((v0 >= tgt) && (v1 >= tgt))) break;
          __builtin_amdgcn_s_sleep(1);
        }
      }
      __builtin_amdgcn_sched_barrier(0);   // pin: A-loads stay after the poll
    }

    // ---- A sources (ring slots written-once, read-fresh) ----
    const unsigned short *aHi, *aLo;
    if (layer == 0) {
      if (w < 4) { aHi = Xhi + (size_t)t * LSLOT;        aLo = Xlo + (size_t)t * LSLOT; }
      else       { aHi = h1hi + (size_t)t * LSLOT;       aLo = h1lo + (size_t)t * LSLOT; }
    } else {
      if (w < 4) { aHi = h1hi + (size_t)(t + 1) * LSLOT; aLo = h1lo + (size_t)(t + 1) * LSLOT; }
      else       { aHi = h2hi + (size_t)t * LSLOT;       aLo = h2lo + (size_t)t * LSLOT; }
    }
    const int aoff = (w & 3) * 256;
    const unsigned short* aH0 = aHi + (size_t)lrow * 1024 + aoff + klo;
    const unsigned short* aL0 = aLo + (size_t)lrow * 1024 + aoff + klo;
    const unsigned short* aH1 = aH0 + 16 * 1024;
    const unsigned short* aL1 = aL0 + 16 * 1024;

    f32x4 acc[2][2] = {};
#pragma unroll
    for (int ks = 0; ks < 8; ++ks) {
      bf16x8 a0h = *reinterpret_cast<const bf16x8*>(aH0 + ks * 32);
      bf16x8 a0l = *reinterpret_cast<const bf16x8*>(aL0 + ks * 32);
      bf16x8 a1h = *reinterpret_cast<const bf16x8*>(aH1 + ks * 32);
      bf16x8 a1l = *reinterpret_cast<const bf16x8*>(aL1 + ks * 32);
#pragma unroll
      for (int nt = 0; nt < 2; ++nt) {
        acc[0][nt] = __builtin_amdgcn_mfma_f32_16x16x32_bf16(a0h, wh[nt][ks], acc[0][nt], 0, 0, 0);
        acc[0][nt] = __builtin_amdgcn_mfma_f32_16x16x32_bf16(a0l, wh[nt][ks], acc[0][nt], 0, 0, 0);
        acc[0][nt] = __builtin_amdgcn_mfma_f32_16x16x32_bf16(a0h, wl[nt][ks], acc[0][nt], 0, 0, 0);
        acc[1][nt] = __builtin_amdgcn_mfma_f32_16x16x32_bf16(a1h, wh[nt][ks], acc[1][nt], 0, 0, 0);
        acc[1][nt] = __builtin_amdgcn_mfma_f32_16x16x32_bf16(a1l, wh[nt][ks], acc[1][nt], 0, 0, 0);
        acc[1][nt] = __builtin_amdgcn_mfma_f32_16x16x32_bf16(a1h, wl[nt][ks], acc[1][nt], 0, 0, 0);
      }
    }

    // C/D (r5-validated): col = lane&15 (n), row = (lane>>4)*4 + j (batch)
    const int zb = (lane >> 4) * 4;
#pragma unroll
    for (int mt = 0; mt < 2; ++mt)
#pragma unroll
      for (int nt = 0; nt < 2; ++nt)
#pragma unroll
        for (int j = 0; j < 4; ++j)
          zl[w][mt * 16 + zb + j][nt * 16 + lrow] = acc[mt][nt][j];
    __syncthreads();

    if (tid < 256) {
      float iv = bi, jv = bj, fv = bff, ov = bo;
#pragma unroll
      for (int ww = 0; ww < 8; ++ww) {
        iv += zl[ww][eb][ec];
        jv += zl[ww][eb][8 + ec];
        fv += zl[ww][eb][16 + ec];
        ov += zl[ww][eb][24 + ec];
      }
      float si = fsigmoid(iv);
      float sf = fsigmoid(fv + 1.f);     // FORGET_BIAS = 1.0
      float so = fsigmoid(ov);
      float tj = ftanh(jv);
      c = c * sf + si * tj;
      float hv = ftanh(c) * so;
      unsigned short hh = f2bf(hv);
      unsigned short hl = f2bf(hv - bf2f(hh));
      int hhp = __shfl_xor((int)hh, 1);
      int hlp = __shfl_xor((int)hl, 1);
      if ((ec & 1) == 0) {
        unsigned uhi = (unsigned)hh | ((unsigned)hhp << 16);
        unsigned ulo = (unsigned)hl | ((unsigned)hlp << 16);
        unsigned off = (unsigned)(eb * 1024 + j0 + ec) >> 1;
        unsigned int* dh = (unsigned int*)((layer ? h2hi : h1hi) + (size_t)(t + 1) * LSLOT) + off;
        unsigned int* dl = (unsigned int*)((layer ? h2lo : h1lo) + (size_t)(t + 1) * LSLOT) + off;
        __hip_atomic_store(dh, uhi, __ATOMIC_RELAXED, __HIP_MEMORY_SCOPE_AGENT);
        __hip_atomic_store(dl, ulo, __ATOMIC_RELAXED, __HIP_MEMORY_SCOPE_AGENT);
      }
    }
    __syncthreads();   // drains all coherent stores (vmcnt=0) + zl reads done
    // RELAXED flag store: data already at the coherence point (drained above),
    // so no release fence (no per-step L2 writeback walk) is needed.
    if (tid == 0)
      __hip_atomic_store(&Fown[wg * 4], (unsigned)(t + 1),
                         __ATOMIC_RELAXED, __HIP_MEMORY_SCOPE_AGENT);
  }
}

// ---------------- MFMA dense GEMM (r5-validated): C = A * B^T + bias ----------
__global__ __launch_bounds__(256) void gemm_bt(
    const unsigned short* __restrict__ A, const unsigned short* __restrict__ B,
    const float* __restrict__ bias, float* __restrict__ C, int M, int N, int K)
{
  __shared__ __align__(16) unsigned short As[128 * 32];
  __shared__ __align__(16) unsigned short Bs[128 * 32];
  const int tid = threadIdx.x, lane = tid & 63, w = tid >> 6;

  const int ntiles = gridDim.x;
  int lid = blockIdx.y * ntiles + blockIdx.x;
  int total = ntiles * gridDim.y;
  int cpx = total >> 3;
  int swz = (lid & 7) * cpx + (lid >> 3);
  int bn = swz % ntiles, bm = swz / ntiles;

  const int wm = (w >> 1) * 64, wn = (w & 1) * 64;
  const int lrow = lane & 15, klo = (lane >> 4) * 8;
  const int l4 = lane >> 2, l2 = lane & 3;

  f32x4 acc[4][4] = {};

  for (int kt = 0; kt < K / 32; ++kt) {
    __syncthreads();
#pragma unroll
    for (int ci = 0; ci < 2; ++ci) {
      int row = w * 32 + ci * 16 + l4;
      async16(A + (size_t)(bm * 128 + row) * K + kt * 32 + l2 * 8,
              (char*)As + (w * 2 + ci) * 1024);
      async16(B + (size_t)(bn * 128 + row) * K + kt * 32 + l2 * 8,
              (char*)Bs + (w * 2 + ci) * 1024);
    }
    __syncthreads();
    bf16x8 a[4], bb[4];
#pragma unroll
    for (int i = 0; i < 4; ++i) {
      a[i]  = *reinterpret_cast<const bf16x8*>(As + (wm + i * 16 + lrow) * 32 + klo);
      bb[i] = *reinterpret_cast<const bf16x8*>(Bs + (wn + i * 16 + lrow) * 32 + klo);
    }
#pragma unroll
    for (int i = 0; i < 4; ++i)
#pragma unroll
      for (int j = 0; j < 4; ++j)
        acc[i][j] = __builtin_amdgcn_mfma_f32_16x16x32_bf16(a[i], bb[j], acc[i][j], 0, 0, 0);
  }

#pragma unroll
  for (int j2 = 0; j2 < 4; ++j2) {
    int col = bn * 128 + wn + j2 * 16 + lrow;
    float bv = bias[col];
#pragma unroll
    for (int i = 0; i < 4; ++i) {
      int rbase = bm * 128 + wm + i * 16 + (lane >> 4) * 4;
#pragma unroll
      for (int j = 0; j < 4; ++j)
        C[(size_t)(rbase + j) * N + col] = acc[i][j2][j] + bv;
    }
  }
}

// ================= host =====================================================
extern "C" void kernel_launch(void* const* d_in, const int* in_sizes, int n_in,
                              void* d_out, int out_size, void* d_ws, size_t ws_size,
                              hipStream_t stream) {
  const int*   ids = (const int*)d_in[0];
  const float* emb = (const float*)d_in[1];
  const float* W0  = (const float*)d_in[2];
  const float* b0  = (const float*)d_in[3];
  const float* W1  = (const float*)d_in[4];
  const float* b1  = (const float*)d_in[5];
  const float* Wd  = (const float*)d_in[6];
  const float* bd  = (const float*)d_in[7];
  float* out = (float*)d_out;

  const size_t ringB = (size_t)(SEQ + 1) * LSLOT * 2;   // 8.45 MB per ring

  // d_out scratch (dead until gemm overwrites all of it): X hi/lo + lo-rings
  unsigned short* Xhi   = (unsigned short*)d_out;
  unsigned short* Xlo   = Xhi + (size_t)ROWS * EMB;
  unsigned short* h1lo  = Xlo + (size_t)ROWS * EMB;
  unsigned short* h2lo  = h1lo + (size_t)(SEQ + 1) * LSLOT;

  char* ws = (char*)d_ws;
  size_t off = 0;
  auto alloc = [&](size_t bytes) {
    char* p = ws + off;
    off += (bytes + 255) & ~(size_t)255;
    return p;
  };
  unsigned int*   F0   = (unsigned int*)alloc(2048);           // 128 flags x 16B
  unsigned int*   F1   = (unsigned int*)alloc(2048);
  unsigned short* h1hi = (unsigned short*)alloc(ringB);
  unsigned short* H2R  = (unsigned short*)alloc(ringB);        // h2-hi ring == H2 output
  size_t regionW = off;
  unsigned short* W0hi = (unsigned short*)alloc((size_t)G4 * 2048 * 2);
  unsigned short* W0lo = (unsigned short*)alloc((size_t)G4 * 2048 * 2);
  unsigned short* W1hi = (unsigned short*)alloc((size_t)G4 * 2048 * 2);
  unsigned short* W1lo = (unsigned short*)alloc((size_t)G4 * 2048 * 2);
  unsigned short* Wdt  = (unsigned short*)(ws + regionW);      // aliases W region post-recurrence
  (void)in_sizes; (void)n_in; (void)out_size; (void)ws_size;   // ws total ~84 MB

  hipMemsetAsync(F0, 0, 4096, stream);                         // F0 + F1 (contiguous)
  hipMemsetAsync(h1hi, 0, LSLOT * 2, stream);
  hipMemsetAsync(H2R, 0, LSLOT * 2, stream);
  hipMemsetAsync(h1lo, 0, LSLOT * 2, stream);
  hipMemsetAsync(h2lo, 0, LSLOT * 2, stream);

  embed_split<<<ROWS, 256, 0, stream>>>(ids, emb, Xhi, Xlo);
  wsplit_kernel<<<dim3(G4 / 32, 2048 / 32), dim3(32, 8), 0, stream>>>(W0, W0hi, W0lo, 2048, G4);
  wsplit_kernel<<<dim3(G4 / 32, 2048 / 32), dim3(32, 8), 0, stream>>>(W1, W1hi, W1lo, 2048, G4);

  lstm_ring<<<256, 512, 0, stream>>>(Xhi, Xlo, W0hi, W0lo, W1hi, W1lo, b0, b1,
                                     h1hi, h1lo, H2R, h2lo, F0, F1);

  transpose_kernel<<<dim3(VOCAB / 32, HID / 32), dim3(32, 8), 0, stream>>>(Wd, Wdt, HID, VOCAB);
  gemm_bt<<<dim3(VOCAB / 128, ROWS / 128), 256, 0, stream>>>(H2R + LSLOT, Wdt, bd, out,
                                                             ROWS, VOCAB, HID);
}

// Round 12
// 1237.414 us; speedup vs baseline: 1.8038x; 1.4206x over previous
//
#include <hip/hip_runtime.h>

#define VOCAB 32000
#define EMB   1024
#define HID   1024
#define SEQ   128
#define BATCH 32
#define ROWS  (SEQ * BATCH)   // 4096
#define G4    (4 * HID)       // 4096
#define SSEG  512             // ushorts per segment: 32 rows x (8 hi + 8 lo)
#define SSLOT 65536           // ushorts per slot: 128 segments

typedef __bf16 bf16x8 __attribute__((ext_vector_type(8)));
typedef float  f32x4  __attribute__((ext_vector_type(4)));

__device__ __forceinline__ unsigned short f2bf(float f) {
  union { float f; unsigned int u; } v; v.f = f;
  unsigned int r = v.u + 0x7fffu + ((v.u >> 16) & 1u);
  return (unsigned short)(r >> 16);
}
__device__ __forceinline__ float bf2f(unsigned short u) {
  union { unsigned int u; float f; } v; v.u = ((unsigned int)u) << 16;
  return v.f;
}

__device__ __forceinline__ void async16(const void* g, void* l) {
  __builtin_amdgcn_global_load_lds(
      (const __attribute__((address_space(1))) void*)g,
      (__attribute__((address_space(3))) void*)l, 16, 0, 0);
}

__device__ __forceinline__ float fsigmoid(float x) {
  return __builtin_amdgcn_rcpf(1.f + __expf(-x));
}
__device__ __forceinline__ float ftanh(float x) {
  return 1.f - 2.f * __builtin_amdgcn_rcpf(__expf(2.f * x) + 1.f);
}

// ------- embedding gather + split, written in PACKED layout [t][seg][row][8h|8l] ----
__global__ void embed_split(const int* __restrict__ ids, const float* __restrict__ emb,
                            unsigned short* __restrict__ Xp) {
  int r = blockIdx.x;                 // t*32 + b
  int t = r >> 5, b = r & 31;
  int row = ids[r];
  int e = threadIdx.x * 4;
  const float4 v = *reinterpret_cast<const float4*>(emb + (size_t)row * EMB + e);
  ushort4 hi, lo;
  hi.x = f2bf(v.x); lo.x = f2bf(v.x - bf2f(hi.x));
  hi.y = f2bf(v.y); lo.y = f2bf(v.y - bf2f(hi.y));
  hi.z = f2bf(v.z); lo.z = f2bf(v.z - bf2f(hi.z));
  hi.w = f2bf(v.w); lo.w = f2bf(v.w - bf2f(hi.w));
  unsigned short* dst = Xp + (size_t)t * SSLOT + (e >> 3) * SSEG + b * 16 + (e & 7);
  *reinterpret_cast<ushort4*>(dst)     = hi;
  *reinterpret_cast<ushort4*>(dst + 8) = lo;
}

// ------------- transpose+split f32 [K][N] -> bf16 hi/lo [N][K] -------------
__global__ void wsplit_kernel(const float* __restrict__ in, unsigned short* __restrict__ hi,
                              unsigned short* __restrict__ lo, int K, int N) {
  __shared__ float t[32][33];
  int n0 = blockIdx.x * 32, k0 = blockIdx.y * 32;
  int tx = threadIdx.x, ty = threadIdx.y;
#pragma unroll
  for (int i = 0; i < 4; ++i)
    t[ty + i * 8][tx] = in[(size_t)(k0 + ty + i * 8) * N + n0 + tx];
  __syncthreads();
#pragma unroll
  for (int i = 0; i < 4; ++i) {
    float v = t[tx][ty + i * 8];
    unsigned short h = f2bf(v);
    hi[(size_t)(n0 + ty + i * 8) * K + k0 + tx] = h;
    lo[(size_t)(n0 + ty + i * 8) * K + k0 + tx] = f2bf(v - bf2f(h));
  }
}

// ------------- transpose f32 [K][N] -> bf16 [N][K] (Wd, r5-validated) -------
__global__ void transpose_kernel(const float* __restrict__ in, unsigned short* __restrict__ out,
                                 int K, int N) {
  __shared__ float t[32][33];
  int n0 = blockIdx.x * 32, k0 = blockIdx.y * 32;
  int tx = threadIdx.x, ty = threadIdx.y;
#pragma unroll
  for (int i = 0; i < 4; ++i)
    t[ty + i * 8][tx] = in[(size_t)(k0 + ty + i * 8) * N + n0 + tx];
  __syncthreads();
#pragma unroll
  for (int i = 0; i < 4; ++i)
    out[(size_t)(n0 + ty + i * 8) * K + k0 + tx] = f2bf(t[tx][ty + i * 8]);
}

// ============ fused 2-layer LSTM: register-resident split-bf16 W, MFMA z-path,
// PACKED block-major ring (coalesced 1KB/block stores, hi+lo same line) +
// per-wave 32-producer RELAXED flag waits. blocks 0..127 L0, 128..255 L1.
__global__ __launch_bounds__(512, 2) void lstm_ring(
    const unsigned short* __restrict__ Xp,        // [128][128][32][16] packed
    const unsigned short* __restrict__ W0hi, const unsigned short* __restrict__ W0lo,
    const unsigned short* __restrict__ W1hi, const unsigned short* __restrict__ W1lo,
    const float* __restrict__ b0, const float* __restrict__ b1,
    unsigned short* __restrict__ H2,              // [4096][1024] flat, for gemm
    unsigned short* h1r, unsigned short* h2r,     // rings [129][128][32][16]
    unsigned int* F0, unsigned int* F1)
{
  __shared__ float zl[8][32][36];

  const int tid   = threadIdx.x;
  const int lane  = tid & 63;
  const int w     = tid >> 6;                // wave 0..7, K-range w*256..+256
  const int layer = blockIdx.x >> 7;
  const int wg    = blockIdx.x & 127;
  const int j0    = wg * 8;
  const int lrow  = lane & 15;
  const int klo   = (lane >> 4) * 8;

  const unsigned short* Whi = layer ? W1hi : W0hi;
  const unsigned short* Wlo = layer ? W1lo : W0lo;
  const float*          bias = layer ? b1 : b0;

  // ---- persistent W fragments (hi+lo, 128 VGPRs) ----
  bf16x8 wh[2][8], wl[2][8];
#pragma unroll
  for (int nt = 0; nt < 2; ++nt) {
    int n = nt * 16 + lrow;
    size_t grow = (size_t)((n >> 3) * 1024 + j0 + (n & 7));
    const unsigned short* bh = Whi + grow * 2048 + w * 256 + klo;
    const unsigned short* bl = Wlo + grow * 2048 + w * 256 + klo;
#pragma unroll
    for (int ks = 0; ks < 8; ++ks) {
      wh[nt][ks] = *reinterpret_cast<const bf16x8*>(bh + ks * 32);
      wl[nt][ks] = *reinterpret_cast<const bf16x8*>(bl + ks * 32);
    }
  }

  const int eb = tid >> 3;
  const int ec = tid & 7;
  const float bi  = bias[j0 + ec];
  const float bj  = bias[1024 + j0 + ec];
  const float bff = bias[2048 + j0 + ec];
  const float bo  = bias[3072 + j0 + ec];
  float c = 0.f;

  unsigned int* Fown = layer ? F1 : F0;

  for (int t = 0; t < SEQ; ++t) {
    // ---- per-wave wait on the 32 producer blocks of this wave's K-slice ----
    {
      const unsigned int* FF = nullptr;
      unsigned tgt = 0; int fb = 0;
      if (layer == 0) {
        if (w >= 4) { FF = F0; tgt = (unsigned)t; fb = (w - 4) * 32; }
      } else {
        if (w < 4) { FF = F0; tgt = (unsigned)(t + 1); fb = w * 32; }
        else       { FF = F1; tgt = (unsigned)t;       fb = (w - 4) * 32; }
      }
      if (FF && tgt) {
        for (;;) {
          unsigned v = (lane < 32)
              ? __hip_atomic_load(FF + (fb + lane) * 4, __ATOMIC_RELAXED,
                                  __HIP_MEMORY_SCOPE_AGENT)
              : 0xFFFFFFFFu;
          if (__all(v >= tgt)) break;
          __builtin_amdgcn_s_sleep(1);
        }
      }
      __builtin_amdgcn_sched_barrier(0);   // pin: A-loads stay after the poll
    }

    // ---- A source (uniform packed addressing for X and h rings) ----
    const unsigned short* pb; int segb;
    if (layer == 0) {
      if (w < 4) { pb = Xp  + (size_t)t * SSLOT;       segb = w * 32; }
      else       { pb = h1r + (size_t)t * SSLOT;       segb = (w - 4) * 32; }
    } else {
      if (w < 4) { pb = h1r + (size_t)(t + 1) * SSLOT; segb = w * 32; }
      else       { pb = h2r + (size_t)t * SSLOT;       segb = (w - 4) * 32; }
    }
    const unsigned short* lanebase = pb + (size_t)(segb + (lane >> 4)) * SSEG + lrow * 16;

    f32x4 acc[2][2] = {};
#pragma unroll
    for (int ks = 0; ks < 8; ++ks) {
      const unsigned short* p = lanebase + ks * (4 * SSEG);
      bf16x8 a0h = *reinterpret_cast<const bf16x8*>(p);
      bf16x8 a0l = *reinterpret_cast<const bf16x8*>(p + 8);
      bf16x8 a1h = *reinterpret_cast<const bf16x8*>(p + 256);   // row lrow+16
      bf16x8 a1l = *reinterpret_cast<const bf16x8*>(p + 264);
#pragma unroll
      for (int nt = 0; nt < 2; ++nt) {
        acc[0][nt] = __builtin_amdgcn_mfma_f32_16x16x32_bf16(a0h, wh[nt][ks], acc[0][nt], 0, 0, 0);
        acc[0][nt] = __builtin_amdgcn_mfma_f32_16x16x32_bf16(a0l, wh[nt][ks], acc[0][nt], 0, 0, 0);
        acc[0][nt] = __builtin_amdgcn_mfma_f32_16x16x32_bf16(a0h, wl[nt][ks], acc[0][nt], 0, 0, 0);
        acc[1][nt] = __builtin_amdgcn_mfma_f32_16x16x32_bf16(a1h, wh[nt][ks], acc[1][nt], 0, 0, 0);
        acc[1][nt] = __builtin_amdgcn_mfma_f32_16x16x32_bf16(a1l, wh[nt][ks], acc[1][nt], 0, 0, 0);
        acc[1][nt] = __builtin_amdgcn_mfma_f32_16x16x32_bf16(a1h, wl[nt][ks], acc[1][nt], 0, 0, 0);
      }
    }

    // C/D (r5-validated): col = lane&15 (n), row = (lane>>4)*4 + j (batch)
    const int zb = (lane >> 4) * 4;
#pragma unroll
    for (int mt = 0; mt < 2; ++mt)
#pragma unroll
      for (int nt = 0; nt < 2; ++nt)
#pragma unroll
        for (int j = 0; j < 4; ++j)
          zl[w][mt * 16 + zb + j][nt * 16 + lrow] = acc[mt][nt][j];
    __syncthreads();

    unsigned short hh = 0;
    if (tid < 256) {
      float iv = bi, jv = bj, fv = bff, ov = bo;
#pragma unroll
      for (int ww = 0; ww < 8; ++ww) {
        iv += zl[ww][eb][ec];
        jv += zl[ww][eb][8 + ec];
        fv += zl[ww][eb][16 + ec];
        ov += zl[ww][eb][24 + ec];
      }
      float si = fsigmoid(iv);
      float sf = fsigmoid(fv + 1.f);     // FORGET_BIAS = 1.0
      float so = fsigmoid(ov);
      float tj = ftanh(jv);
      c = c * sf + si * tj;
      float hv = ftanh(c) * so;
      hh = f2bf(hv);
      unsigned short hl = f2bf(hv - bf2f(hh));
      int hhp = __shfl_xor((int)hh, 1);
      int hlp = __shfl_xor((int)hl, 1);
      if ((ec & 1) == 0) {
        unsigned uhi = (unsigned)hh | ((unsigned)hhp << 16);
        unsigned ulo = (unsigned)hl | ((unsigned)hlp << 16);
        // own segment: contiguous 1KB, coalesced across the block's 128 stores
        unsigned int* du = (unsigned int*)((layer ? h2r : h1r)
                           + (size_t)(t + 1) * SSLOT + wg * SSEG);
        unsigned uoff = (unsigned)(eb * 8 + (ec >> 1));
        __hip_atomic_store(du + uoff,     uhi, __ATOMIC_RELAXED, __HIP_MEMORY_SCOPE_AGENT);
        __hip_atomic_store(du + uoff + 4, ulo, __ATOMIC_RELAXED, __HIP_MEMORY_SCOPE_AGENT);
      }
    }
    __syncthreads();   // drains ring stores (vmcnt=0) + zl reads done
    if (tid == 0)
      __hip_atomic_store(&Fown[wg * 4], (unsigned)(t + 1),
                         __ATOMIC_RELAXED, __HIP_MEMORY_SCOPE_AGENT);
    // off-critical-path flat H2 write for the gemm (drained by next iter's barrier)
    if (layer && tid < 256)
      H2[(size_t)(t * 32 + eb) * 1024 + j0 + ec] = hh;
  }
}

// ---------------- MFMA dense GEMM (r5-validated): C = A * B^T + bias ----------
__global__ __launch_bounds__(256) void gemm_bt(
    const unsigned short* __restrict__ A, const unsigned short* __restrict__ B,
    const float* __restrict__ bias, float* __restrict__ C, int M, int N, int K)
{
  __shared__ __align__(16) unsigned short As[128 * 32];
  __shared__ __align__(16) unsigned short Bs[128 * 32];
  const int tid = threadIdx.x, lane = tid & 63, w = tid >> 6;

  const int ntiles = gridDim.x;
  int lid = blockIdx.y * ntiles + blockIdx.x;
  int total = ntiles * gridDim.y;
  int cpx = total >> 3;
  int swz = (lid & 7) * cpx + (lid >> 3);
  int bn = swz % ntiles, bm = swz / ntiles;

  const int wm = (w >> 1) * 64, wn = (w & 1) * 64;
  const int lrow = lane & 15, klo = (lane >> 4) * 8;
  const int l4 = lane >> 2, l2 = lane & 3;

  f32x4 acc[4][4] = {};

  for (int kt = 0; kt < K / 32; ++kt) {
    __syncthreads();
#pragma unroll
    for (int ci = 0; ci < 2; ++ci) {
      int row = w * 32 + ci * 16 + l4;
      async16(A + (size_t)(bm * 128 + row) * K + kt * 32 + l2 * 8,
              (char*)As + (w * 2 + ci) * 1024);
      async16(B + (size_t)(bn * 128 + row) * K + kt * 32 + l2 * 8,
              (char*)Bs + (w * 2 + ci) * 1024);
    }
    __syncthreads();
    bf16x8 a[4], bb[4];
#pragma unroll
    for (int i = 0; i < 4; ++i) {
      a[i]  = *reinterpret_cast<const bf16x8*>(As + (wm + i * 16 + lrow) * 32 + klo);
      bb[i] = *reinterpret_cast<const bf16x8*>(Bs + (wn + i * 16 + lrow) * 32 + klo);
    }
#pragma unroll
    for (int i = 0; i < 4; ++i)
#pragma unroll
      for (int j = 0; j < 4; ++j)
        acc[i][j] = __builtin_amdgcn_mfma_f32_16x16x32_bf16(a[i], bb[j], acc[i][j], 0, 0, 0);
  }

#pragma unroll
  for (int j2 = 0; j2 < 4; ++j2) {
    int col = bn * 128 + wn + j2 * 16 + lrow;
    float bv = bias[col];
#pragma unroll
    for (int i = 0; i < 4; ++i) {
      int rbase = bm * 128 + wm + i * 16 + (lane >> 4) * 4;
#pragma unroll
      for (int j = 0; j < 4; ++j)
        C[(size_t)(rbase + j) * N + col] = acc[i][j2][j] + bv;
    }
  }
}

// ================= host =====================================================
extern "C" void kernel_launch(void* const* d_in, const int* in_sizes, int n_in,
                              void* d_out, int out_size, void* d_ws, size_t ws_size,
                              hipStream_t stream) {
  const int*   ids = (const int*)d_in[0];
  const float* emb = (const float*)d_in[1];
  const float* W0  = (const float*)d_in[2];
  const float* b0  = (const float*)d_in[3];
  const float* W1  = (const float*)d_in[4];
  const float* b1  = (const float*)d_in[5];
  const float* Wd  = (const float*)d_in[6];
  const float* bd  = (const float*)d_in[7];
  float* out = (float*)d_out;

  // d_out scratch (dead until gemm overwrites all of it): packed X + both rings
  unsigned short* Xp  = (unsigned short*)d_out;                 // 128 slots, 16.8 MB
  unsigned short* h1r = Xp + (size_t)SEQ * SSLOT;               // 129 slots, 16.9 MB
  unsigned short* h2r = h1r + (size_t)(SEQ + 1) * SSLOT;        // 129 slots, 16.9 MB

  char* ws = (char*)d_ws;
  size_t off = 0;
  auto alloc = [&](size_t bytes) {
    char* p = ws + off;
    off += (bytes + 255) & ~(size_t)255;
    return p;
  };
  unsigned int*   F0 = (unsigned int*)alloc(2048);              // 128 flags x 16B
  unsigned int*   F1 = (unsigned int*)alloc(2048);
  unsigned short* H2 = (unsigned short*)alloc((size_t)ROWS * HID * 2);   // 8.4 MB
  size_t regionW = off;
  unsigned short* W0hi = (unsigned short*)alloc((size_t)G4 * 2048 * 2);
  unsigned short* W0lo = (unsigned short*)alloc((size_t)G4 * 2048 * 2);
  unsigned short* W1hi = (unsigned short*)alloc((size_t)G4 * 2048 * 2);
  unsigned short* W1lo = (unsigned short*)alloc((size_t)G4 * 2048 * 2);
  unsigned short* Wdt  = (unsigned short*)(ws + regionW);       // aliases W region post-LSTM
  (void)in_sizes; (void)n_in; (void)out_size; (void)ws_size;    // ws total ~76 MB

  hipMemsetAsync(F0, 0, 4096, stream);                          // F0 + F1
  hipMemsetAsync(h1r, 0, (size_t)SSLOT * 2, stream);            // ring slot 0
  hipMemsetAsync(h2r, 0, (size_t)SSLOT * 2, stream);

  embed_split<<<ROWS, 256, 0, stream>>>(ids, emb, Xp);
  wsplit_kernel<<<dim3(G4 / 32, 2048 / 32), dim3(32, 8), 0, stream>>>(W0, W0hi, W0lo, 2048, G4);
  wsplit_kernel<<<dim3(G4 / 32, 2048 / 32), dim3(32, 8), 0, stream>>>(W1, W1hi, W1lo, 2048, G4);

  lstm_ring<<<256, 512, 0, stream>>>(Xp, W0hi, W0lo, W1hi, W1lo, b0, b1,
                                     H2, h1r, h2r, F0, F1);

  transpose_kernel<<<dim3(VOCAB / 32, HID / 32), dim3(32, 8), 0, stream>>>(Wd, Wdt, HID, VOCAB);
  gemm_bt<<<dim3(VOCAB / 128, ROWS / 128), 256, 0, stream>>>(H2, Wdt, bd, out,
                                                             ROWS, VOCAB, HID);
}

// Round 14
// 1216.627 us; speedup vs baseline: 1.8346x; 1.0171x over previous
//
#include <hip/hip_runtime.h>

#define VOCAB 32000
#define EMB   1024
#define HID   1024
#define SEQ   128
#define BATCH 32
#define ROWS  (SEQ * BATCH)   // 4096
#define G4    (4 * HID)       // 4096
#define SSEG  512             // ushorts per segment: 32 rows x (8 hi + 8 lo)
#define SSLOT 65536           // ushorts per slot: 128 segments

typedef __bf16 bf16x8 __attribute__((ext_vector_type(8)));
typedef float  f32x4  __attribute__((ext_vector_type(4)));

__device__ __forceinline__ unsigned short f2bf(float f) {
  union { float f; unsigned int u; } v; v.f = f;
  unsigned int r = v.u + 0x7fffu + ((v.u >> 16) & 1u);
  return (unsigned short)(r >> 16);
}
__device__ __forceinline__ float bf2f(unsigned short u) {
  union { unsigned int u; float f; } v; v.u = ((unsigned int)u) << 16;
  return v.f;
}

__device__ __forceinline__ void async16(const void* g, void* l) {
  __builtin_amdgcn_global_load_lds(
      (const __attribute__((address_space(1))) void*)g,
      (__attribute__((address_space(3))) void*)l, 16, 0, 0);
}

__device__ __forceinline__ float fsigmoid(float x) {
  return __builtin_amdgcn_rcpf(1.f + __expf(-x));
}
__device__ __forceinline__ float ftanh(float x) {
  return 1.f - 2.f * __builtin_amdgcn_rcpf(__expf(2.f * x) + 1.f);
}

// ------- embedding gather + split, PACKED layout [t][seg][row][8h|8l] ----
__global__ void embed_split(const int* __restrict__ ids, const float* __restrict__ emb,
                            unsigned short* __restrict__ Xp) {
  int r = blockIdx.x;                 // t*32 + b
  int t = r >> 5, b = r & 31;
  int row = ids[r];
  int e = threadIdx.x * 4;
  const float4 v = *reinterpret_cast<const float4*>(emb + (size_t)row * EMB + e);
  ushort4 hi, lo;
  hi.x = f2bf(v.x); lo.x = f2bf(v.x - bf2f(hi.x));
  hi.y = f2bf(v.y); lo.y = f2bf(v.y - bf2f(hi.y));
  hi.z = f2bf(v.z); lo.z = f2bf(v.z - bf2f(hi.z));
  hi.w = f2bf(v.w); lo.w = f2bf(v.w - bf2f(hi.w));
  unsigned short* dst = Xp + (size_t)t * SSLOT + (e >> 3) * SSEG + b * 16 + (e & 7);
  *reinterpret_cast<ushort4*>(dst)     = hi;
  *reinterpret_cast<ushort4*>(dst + 8) = lo;
}

// ------------- transpose f32 [K][N] -> bf16 [N][K] (Wd, r5-validated) -------
__global__ void transpose_kernel(const float* __restrict__ in, unsigned short* __restrict__ out,
                                 int K, int N) {
  __shared__ float t[32][33];
  int n0 = blockIdx.x * 32, k0 = blockIdx.y * 32;
  int tx = threadIdx.x, ty = threadIdx.y;
#pragma unroll
  for (int i = 0; i < 4; ++i)
    t[ty + i * 8][tx] = in[(size_t)(k0 + ty + i * 8) * N + n0 + tx];
  __syncthreads();
#pragma unroll
  for (int i = 0; i < 4; ++i)
    out[(size_t)(n0 + ty + i * 8) * K + k0 + tx] = f2bf(t[tx][ty + i * 8]);
}

// ============ fused 2-layer LSTM (r12-proven sync structure): register-resident
// split-bf16 W (computed in-register from raw f32 W — r13-validated values),
// MFMA z-path, packed block-major ring + per-wave 32-producer RELAXED flags.
__global__ __launch_bounds__(512, 2) void lstm_ring(
    const unsigned short* __restrict__ Xp,        // [128][128][32][16] packed
    const float* __restrict__ W0, const float* __restrict__ W1,
    const float* __restrict__ b0, const float* __restrict__ b1,
    unsigned short* __restrict__ H2,              // [4096][1024] flat, for gemm
    unsigned short* h1r, unsigned short* h2r,     // rings [129][128][32][16]
    unsigned int* F0, unsigned int* F1)
{
  __shared__ float zl[8][32][36];

  const int tid   = threadIdx.x;
  const int lane  = tid & 63;
  const int w     = tid >> 6;                // wave 0..7, K-range w*256..+256
  const int layer = blockIdx.x >> 7;
  const int wg    = blockIdx.x & 127;
  const int j0    = wg * 8;
  const int lrow  = lane & 15;
  const int klo   = (lane >> 4) * 8;

  const float* Wraw = layer ? W1 : W0;
  const float* bias = layer ? b1 : b0;

  // ---- W prologue: hi/lo split in-register from raw f32 W (r13-validated) ----
  bf16x8 wh[2][8], wl[2][8];
#pragma unroll
  for (int nt = 0; nt < 2; ++nt) {
    int n   = nt * 16 + lrow;
    int col = (n >> 3) * 1024 + j0 + (n & 7);
#pragma unroll
    for (int ks = 0; ks < 8; ++ks) {
      alignas(16) unsigned short th[8], tl[8];
#pragma unroll
      for (int e = 0; e < 8; ++e) {
        float v = Wraw[(size_t)(w * 256 + ks * 32 + klo + e) * G4 + col];
        th[e] = f2bf(v);
        tl[e] = f2bf(v - bf2f(th[e]));
      }
      wh[nt][ks] = *reinterpret_cast<bf16x8*>(th);
      wl[nt][ks] = *reinterpret_cast<bf16x8*>(tl);
    }
  }

  const int eb = tid >> 3;
  const int ec = tid & 7;
  const float bi  = bias[j0 + ec];
  const float bj  = bias[1024 + j0 + ec];
  const float bff = bias[2048 + j0 + ec];
  const float bo  = bias[3072 + j0 + ec];
  float c = 0.f;

  unsigned int* Fown = layer ? F1 : F0;

  for (int t = 0; t < SEQ; ++t) {
    // ---- per-wave wait on the 32 producer blocks of this wave's K-slice ----
    {
      const unsigned int* FF = nullptr;
      unsigned tgt = 0; int fb = 0;
      if (layer == 0) {
        if (w >= 4) { FF = F0; tgt = (unsigned)t; fb = (w - 4) * 32; }
      } else {
        if (w < 4) { FF = F0; tgt = (unsigned)(t + 1); fb = w * 32; }
        else       { FF = F1; tgt = (unsigned)t;       fb = (w - 4) * 32; }
      }
      if (FF && tgt) {
        for (;;) {
          unsigned v = (lane < 32)
              ? __hip_atomic_load(FF + (fb + lane) * 4, __ATOMIC_RELAXED,
                                  __HIP_MEMORY_SCOPE_AGENT)
              : 0xFFFFFFFFu;
          if (__all(v >= tgt)) break;
          __builtin_amdgcn_s_sleep(1);
        }
      }
      __builtin_amdgcn_sched_barrier(0);   // pin: A-loads stay after the poll
    }

    // ---- A source (uniform packed addressing for X and h rings) ----
    const unsigned short* pb; int segb;
    if (layer == 0) {
      if (w < 4) { pb = Xp  + (size_t)t * SSLOT;       segb = w * 32; }
      else       { pb = h1r + (size_t)t * SSLOT;       segb = (w - 4) * 32; }
    } else {
      if (w < 4) { pb = h1r + (size_t)(t + 1) * SSLOT; segb = w * 32; }
      else       { pb = h2r + (size_t)t * SSLOT;       segb = (w - 4) * 32; }
    }
    const unsigned short* lanebase = pb + (size_t)(segb + (lane >> 4)) * SSEG + lrow * 16;

    f32x4 acc[2][2] = {};
#pragma unroll
    for (int ks = 0; ks < 8; ++ks) {
      const unsigned short* p = lanebase + ks * (4 * SSEG);
      bf16x8 a0h = *reinterpret_cast<const bf16x8*>(p);
      bf16x8 a0l = *reinterpret_cast<const bf16x8*>(p + 8);
      bf16x8 a1h = *reinterpret_cast<const bf16x8*>(p + 256);   // row lrow+16
      bf16x8 a1l = *reinterpret_cast<const bf16x8*>(p + 264);
#pragma unroll
      for (int nt = 0; nt < 2; ++nt) {
        acc[0][nt] = __builtin_amdgcn_mfma_f32_16x16x32_bf16(a0h, wh[nt][ks], acc[0][nt], 0, 0, 0);
        acc[0][nt] = __builtin_amdgcn_mfma_f32_16x16x32_bf16(a0l, wh[nt][ks], acc[0][nt], 0, 0, 0);
        acc[0][nt] = __builtin_amdgcn_mfma_f32_16x16x32_bf16(a0h, wl[nt][ks], acc[0][nt], 0, 0, 0);
        acc[1][nt] = __builtin_amdgcn_mfma_f32_16x16x32_bf16(a1h, wh[nt][ks], acc[1][nt], 0, 0, 0);
        acc[1][nt] = __builtin_amdgcn_mfma_f32_16x16x32_bf16(a1l, wh[nt][ks], acc[1][nt], 0, 0, 0);
        acc[1][nt] = __builtin_amdgcn_mfma_f32_16x16x32_bf16(a1h, wl[nt][ks], acc[1][nt], 0, 0, 0);
      }
    }

    // C/D (r5-validated): col = lane&15 (n), row = (lane>>4)*4 + j (batch)
    const int zb = (lane >> 4) * 4;
#pragma unroll
    for (int mt = 0; mt < 2; ++mt)
#pragma unroll
      for (int nt = 0; nt < 2; ++nt)
#pragma unroll
        for (int j = 0; j < 4; ++j)
          zl[w][mt * 16 + zb + j][nt * 16 + lrow] = acc[mt][nt][j];
    __syncthreads();

    unsigned short hh = 0;
    if (tid < 256) {
      float iv = bi, jv = bj, fv = bff, ov = bo;
#pragma unroll
      for (int ww = 0; ww < 8; ++ww) {
        iv += zl[ww][eb][ec];
        jv += zl[ww][eb][8 + ec];
        fv += zl[ww][eb][16 + ec];
        ov += zl[ww][eb][24 + ec];
      }
      float si = fsigmoid(iv);
      float sf = fsigmoid(fv + 1.f);     // FORGET_BIAS = 1.0
      float so = fsigmoid(ov);
      float tj = ftanh(jv);
      c = c * sf + si * tj;
      float hv = ftanh(c) * so;
      hh = f2bf(hv);
      unsigned short hl = f2bf(hv - bf2f(hh));
      int hhp = __shfl_xor((int)hh, 1);
      int hlp = __shfl_xor((int)hl, 1);
      if ((ec & 1) == 0) {
        unsigned uhi = (unsigned)hh | ((unsigned)hhp << 16);
        unsigned ulo = (unsigned)hl | ((unsigned)hlp << 16);
        unsigned int* du = (unsigned int*)((layer ? h2r : h1r)
                           + (size_t)(t + 1) * SSLOT + wg * SSEG);
        unsigned uoff = (unsigned)(eb * 8 + (ec >> 1));
        __hip_atomic_store(du + uoff,     uhi, __ATOMIC_RELAXED, __HIP_MEMORY_SCOPE_AGENT);
        __hip_atomic_store(du + uoff + 4, ulo, __ATOMIC_RELAXED, __HIP_MEMORY_SCOPE_AGENT);
      }
    }
    __syncthreads();   // drains ring stores (vmcnt=0) + zl reads done
    if (tid == 0)
      __hip_atomic_store(&Fown[wg * 4], (unsigned)(t + 1),
                         __ATOMIC_RELAXED, __HIP_MEMORY_SCOPE_AGENT);
    // off-critical-path flat H2 write for the gemm (next dispatch)
    if (layer && tid < 256)
      H2[(size_t)(t * 32 + eb) * 1024 + j0 + ec] = hh;
  }
}

// -------- MFMA dense GEMM (r5-validated structure + T2 XOR-swizzle) ---------
// Swizzle (rule #21): linear global_load_lds dest + pre-swizzled global SOURCE
// chunk (l2 ^ ((row>>1)&3)) + same XOR on the ds_read side. 8-way -> 2-way.
__global__ __launch_bounds__(256) void gemm_bt(
    const unsigned short* __restrict__ A, const unsigned short* __restrict__ B,
    const float* __restrict__ bias, float* __restrict__ C, int M, int N, int K)
{
  __shared__ __align__(16) unsigned short As[128 * 32];
  __shared__ __align__(16) unsigned short Bs[128 * 32];
  const int tid = threadIdx.x, lane = tid & 63, w = tid >> 6;

  const int ntiles = gridDim.x;
  int lid = blockIdx.y * ntiles + blockIdx.x;
  int total = ntiles * gridDim.y;
  int cpx = total >> 3;
  int swz = (lid & 7) * cpx + (lid >> 3);
  int bn = swz % ntiles, bm = swz / ntiles;

  const int wm = (w >> 1) * 64, wn = (w & 1) * 64;
  const int lrow = lane & 15;
  const int l4 = lane >> 2, l2 = lane & 3;

  f32x4 acc[4][4] = {};

  for (int kt = 0; kt < K / 32; ++kt) {
    __syncthreads();
#pragma unroll
    for (int ci = 0; ci < 2; ++ci) {
      int row = w * 32 + ci * 16 + l4;
      int sw  = l2 ^ ((row >> 1) & 3);          // pre-swizzled source chunk
      async16(A + (size_t)(bm * 128 + row) * K + kt * 32 + sw * 8,
              (char*)As + (w * 2 + ci) * 1024);
      async16(B + (size_t)(bn * 128 + row) * K + kt * 32 + sw * 8,
              (char*)Bs + (w * 2 + ci) * 1024);
    }
    __syncthreads();
    bf16x8 a[4], bb[4];
#pragma unroll
    for (int i = 0; i < 4; ++i) {
      int ra = wm + i * 16 + lrow;
      int rb = wn + i * 16 + lrow;
      a[i]  = *reinterpret_cast<const bf16x8*>(As + ra * 32 + (((lane >> 4) ^ ((ra >> 1) & 3)) * 8));
      bb[i] = *reinterpret_cast<const bf16x8*>(Bs + rb * 32 + (((lane >> 4) ^ ((rb >> 1) & 3)) * 8));
    }
#pragma unroll
    for (int i = 0; i < 4; ++i)
#pragma unroll
      for (int j = 0; j < 4; ++j)
        acc[i][j] = __builtin_amdgcn_mfma_f32_16x16x32_bf16(a[i], bb[j], acc[i][j], 0, 0, 0);
  }

#pragma unroll
  for (int j2 = 0; j2 < 4; ++j2) {
    int col = bn * 128 + wn + j2 * 16 + lrow;
    float bv = bias[col];
#pragma unroll
    for (int i = 0; i < 4; ++i) {
      int rbase = bm * 128 + wm + i * 16 + (lane >> 4) * 4;
#pragma unroll
      for (int j = 0; j < 4; ++j)
        C[(size_t)(rbase + j) * N + col] = acc[i][j2][j] + bv;
    }
  }
}

// ================= host =====================================================
extern "C" void kernel_launch(void* const* d_in, const int* in_sizes, int n_in,
                              void* d_out, int out_size, void* d_ws, size_t ws_size,
                              hipStream_t stream) {
  const int*   ids = (const int*)d_in[0];
  const float* emb = (const float*)d_in[1];
  const float* W0  = (const float*)d_in[2];
  const float* b0  = (const float*)d_in[3];
  const float* W1  = (const float*)d_in[4];
  const float* b1  = (const float*)d_in[5];
  const float* Wd  = (const float*)d_in[6];
  const float* bd  = (const float*)d_in[7];
  float* out = (float*)d_out;

  // d_out scratch (dead before gemm overwrites all of it): packed X + both rings
  unsigned short* Xp  = (unsigned short*)d_out;                 // 128 slots, 16.8 MB
  unsigned short* h1r = Xp + (size_t)SEQ * SSLOT;               // 129 slots, 16.9 MB
  unsigned short* h2r = h1r + (size_t)(SEQ + 1) * SSLOT;        // 129 slots, 16.9 MB

  char* ws = (char*)d_ws;
  size_t off = 0;
  auto alloc = [&](size_t bytes) {
    char* p = ws + off;
    off += (bytes + 255) & ~(size_t)255;
    return p;
  };
  unsigned int*   F0  = (unsigned int*)alloc(2048);             // 128 flags x 16B
  unsigned int*   F1  = (unsigned int*)alloc(2048);
  unsigned short* H2  = (unsigned short*)alloc((size_t)ROWS * HID * 2);   //  8.4 MB
  unsigned short* Wdt = (unsigned short*)alloc((size_t)VOCAB * HID * 2);  // 65.5 MB
  (void)in_sizes; (void)n_in; (void)out_size; (void)ws_size;    // ws total ~74 MB

  hipMemsetAsync(F0, 0, 4096, stream);                          // F0 + F1
  hipMemsetAsync(h1r, 0, (size_t)SSLOT * 2, stream);            // ring slot 0
  hipMemsetAsync(h2r, 0, (size_t)SSLOT * 2, stream);

  embed_split<<<ROWS, 256, 0, stream>>>(ids, emb, Xp);
  transpose_kernel<<<dim3(VOCAB / 32, HID / 32), dim3(32, 8), 0, stream>>>(Wd, Wdt, HID, VOCAB);

  lstm_ring<<<256, 512, 0, stream>>>(Xp, W0, W1, b0, b1, H2, h1r, h2r, F0, F1);

  gemm_bt<<<dim3(VOCAB / 128, ROWS / 128), 256, 0, stream>>>(H2, Wdt, bd, out,
                                                             ROWS, VOCAB, HID);
}